// Round 19
// baseline (95417.804 us; speedup 1.0000x reference)
//
#include <hip/hip_runtime.h>

// GRU  B=128, T=1024, IN=256, H=512, OUT=1  (all fp32)
//
// v18: 8-WAY GROUP MULTIPLEXING. r12-r18 proved ~11.5us/step is the
// irreducible latency of ONE cross-CU h-exchange (insensitive to compute
// engine, barriers, scope, contention). The 8 sample-groups are independent
// recurrences with IDENTICAL weights -> one wg can serve its j-slice for all
// 8 groups with zero extra weight state. 32 persistent wgs (one per j-slice
// w), each round loops g=0..7 running the v13-validated phase for group g.
// While group g's h propagates (~L=10us), the wg processes 7 other groups
// (~8-10us) -> poll is a no-op on return. round = max(8*phase, L+phase)
// -> ~1.2-1.5us per effective step. Latency-bound -> throughput-bound.
// Phase internals = v13/v17 verbatim (both passed): split-bf16 3-pass MFMA
// (A-hi VGPR, A-lo LDS), U staged hi/lo (pitch 776), ds_add acc, tid<256
// gates, packed (hi<<16|lo) h, private-sector mailbox flags, sleep(1),
// 1<<22 guard, separate head kernel.

#define B_    128
#define T_    1024
#define IN_   256
#define H_    512
#define NGRP  8
#define NWG   32
#define SGRP  16
#define JT    16
#define NT    512
#define RWU   776                          // U row pitch (bf16 elems); *2B = 1552
#define U_HI_OFF   0
#define U_LO_OFF   (SGRP*RWU*2)            // 24,832
#define WLO_OFF    (2*SGRP*RWU*2)          // 49,664
#define ACC_OFF    (WLO_OFF + 8*9*64*16)   // 123,392
#define LDS_DYN    (ACC_OFF + 4*16*17*4)   // 127,744 B

typedef __attribute__((ext_vector_type(8))) short bf16x8;
typedef __attribute__((ext_vector_type(4))) float f32x4;
union BCast { uint4 u; bf16x8 b; unsigned short s[8]; };

#define MFMA(a,b,c) __builtin_amdgcn_mfma_f32_16x16x32_bf16((a),(b),(c),0,0,0)

__device__ __forceinline__ float sig_(float v){ return 1.0f/(1.0f + __expf(-v)); }
__device__ __forceinline__ float tanh_(float v){
  float e = __expf(2.0f*v);
  return 1.0f - 2.0f/(e + 1.0f);
}
__device__ __forceinline__ unsigned short bf16rn(float f){
  unsigned u = __float_as_uint(f);
  return (unsigned short)((u + 0x7FFFu + ((u>>16)&1u)) >> 16);
}

// IF-coherent ops (sc0 sc1, proven v13/v14/v17).
#define CLOADU4(dst, p) asm volatile("global_load_dwordx4 %0, %1, off sc0 sc1" : "=v"(dst) : "v"(p) : "memory")
#define CLOADI(dst, p)  asm volatile("global_load_dword %0, %1, off sc0 sc1"   : "=v"(dst) : "v"(p) : "memory")
#define CSTOREU(p, v)   asm volatile("global_store_dword %0, %1, off sc0 sc1"  :: "v"(p), "v"(v) : "memory")
#define VWAIT0()        do{ asm volatile("s_waitcnt vmcnt(0)" ::: "memory"); __builtin_amdgcn_sched_barrier(0); }while(0)

// poll MY private 128B mailbox block for group g (32 producer slots).
__device__ __forceinline__ int poll_mbox(const int* blk, int lane, int target){
  const int* fp = blk + (lane & 31);
  int guard = 0;
  for (;;){
    int fv;
    CLOADI(fv, fp);
    asm volatile("s_waitcnt vmcnt(0)" ::: "memory");
    if (__all(fv >= target)) return 0;
    __builtin_amdgcn_s_sleep(1);
    if (++guard > (1<<22)) return 1;
  }
}

__global__ void __launch_bounds__(NT, 2)
rnn_persist(const float* __restrict__ x, const float* __restrict__ W_ih,
            const float* __restrict__ W_hh, const float* __restrict__ bias,
            const float* __restrict__ bias_n, unsigned* __restrict__ h_buf,
            int* __restrict__ mbox)
{
  extern __shared__ char lds[];
  unsigned short* Uhi = (unsigned short*)(lds + U_HI_OFF);
  unsigned short* Ulo = (unsigned short*)(lds + U_LO_OFF);
  char*  Wlo  = lds + WLO_OFF;
  float* accb = (float*)(lds + ACC_OFF);

  const int w   = (int)blockIdx.x;     // j-slice [0,32)
  const int tid = (int)threadIdx.x;
  const int w8  = tid >> 6;            // wave [0,8)
  const int l   = tid & 63;            // lane
  const int jl  = l & 15;
  const int kq  = l >> 4;
  const int jg_l = w*JT + jl;

  // ---- init: A-fragments (shared by all 8 groups). hi->VGPR, lo->LDS ----
  bf16x8 ahi[9];
#pragma unroll
  for (int ci=0; ci<3; ci++){
    const int c = 3*w8 + ci;
#pragma unroll
    for (int gi=0; gi<3; gi++){
      const int f = 3*ci + gi;
      const int grow = gi*H_ + jg_l;
      const float* p = (c < 8)
        ? (W_ih + (size_t)grow*IN_ + (32*c + 8*kq))
        : (W_hh + (size_t)grow*H_  + (32*c - 256 + 8*kq));
      const float4 v0 = *(const float4*)p;
      const float4 v1 = *(const float4*)(p+4);
      const float vv[8] = {v0.x,v0.y,v0.z,v0.w,v1.x,v1.y,v1.z,v1.w};
      BCast hi8, lo8;
#pragma unroll
      for (int i=0;i<8;i++){
        const unsigned short h = bf16rn(vv[i]);
        hi8.s[i] = h;
        lo8.s[i] = bf16rn(vv[i] - __uint_as_float(((unsigned)h)<<16));
      }
      ahi[f] = hi8.b;
      *(bf16x8*)(Wlo + ((size_t)(w8*9 + f)*64 + l)*16) = lo8.b;
    }
  }
  float br, bz, bni, bnh;
  { const int jj = w*JT + (tid & 15);
    br = bias[jj]; bz = bias[H_+jj]; bni = bias[2*H_+jj]; bnh = bias_n[jj]; }
  __syncthreads();                     // Wlo visible

  unsigned* const hb0 = h_buf;
  unsigned* const hb1 = h_buf + (size_t)B_*H_;
  int dead = 0;

  for (int t=0; t<T_; ++t){
    const unsigned* hc = (t & 1) ? hb1 : hb0;
    unsigned*      hnx = (t & 1) ? hb0 : hb1;

    for (int g=0; g<NGRP; ++g){        // 8-way multiplexed groups
      const int b0 = g*SGRP;

      // ---- zero acc buffer (prev phase ended at barrier D) ----
      for (int i=tid; i<4*16*17; i+=NT) accb[i] = 0.f;

      // ---- x-stage: fp32 -> bf16 hi/lo -> U[0:256) ----
      {
        const int ss = tid>>5, c2 = tid&31;
        const float* xp = x + ((size_t)(b0+ss)*T_ + (size_t)t)*IN_ + c2*8;
        const float4 a = *(const float4*)xp;
        const float4 b = *(const float4*)(xp+4);
        const float vv[8] = {a.x,a.y,a.z,a.w,b.x,b.y,b.z,b.w};
        unsigned hw[4], lw[4];
#pragma unroll
        for (int q=0;q<4;q++){
          const unsigned short h0 = bf16rn(vv[2*q]);
          const unsigned short h1 = bf16rn(vv[2*q+1]);
          const float f0 = __uint_as_float(((unsigned)h0)<<16);
          const float f1 = __uint_as_float(((unsigned)h1)<<16);
          const unsigned short l0 = bf16rn(vv[2*q]-f0);
          const unsigned short l1 = bf16rn(vv[2*q+1]-f1);
          hw[q] = (unsigned)h0 | ((unsigned)h1<<16);
          lw[q] = (unsigned)l0 | ((unsigned)l1<<16);
        }
        *(uint4*)((char*)Uhi + ss*1552 + c2*16) = make_uint4(hw[0],hw[1],hw[2],hw[3]);
        *(uint4*)((char*)Ulo + ss*1552 + c2*16) = make_uint4(lw[0],lw[1],lw[2],lw[3]);
      }

      // ---- wave0 polls my private mailbox for group g ----
      if (tid < 64 && t > 0 && !dead)
        dead = poll_mbox(mbox + (w*NGRP + g)*32, l, t);
      __syncthreads();                 // P: h^t(g) globally visible

      // ---- h-stage: packed u32 -> split hi/lo -> U[256:768) ----
      {
        const int ss = tid>>5, c2 = tid&31;
        const unsigned* hp = hc + (size_t)(b0+ss)*H_ + c2*16;
        uint4 p0,p1,p2,p3;
        CLOADU4(p0, hp); CLOADU4(p1, hp+4); CLOADU4(p2, hp+8); CLOADU4(p3, hp+12);
        VWAIT0();
        const unsigned P[16] = {p0.x,p0.y,p0.z,p0.w, p1.x,p1.y,p1.z,p1.w,
                                p2.x,p2.y,p2.z,p2.w, p3.x,p3.y,p3.z,p3.w};
        unsigned hwv[8], lwv[8];
#pragma unroll
        for (int q=0;q<8;q++){
          hwv[q] = (P[2*q]>>16) | (P[2*q+1] & 0xFFFF0000u);
          lwv[q] = (P[2*q] & 0xFFFFu) | (P[2*q+1]<<16);
        }
        char* dh = (char*)Uhi + ss*1552 + 512 + c2*32;
        char* dl = (char*)Ulo + ss*1552 + 512 + c2*32;
        *(uint4*)dh      = make_uint4(hwv[0],hwv[1],hwv[2],hwv[3]);
        *(uint4*)(dh+16) = make_uint4(hwv[4],hwv[5],hwv[6],hwv[7]);
        *(uint4*)dl      = make_uint4(lwv[0],lwv[1],lwv[2],lwv[3]);
        *(uint4*)(dl+16) = make_uint4(lwv[4],lwv[5],lwv[6],lwv[7]);
      }
      __syncthreads();                 // B: U complete

      // ---- MFMA: 3 chunks x {r,z,ni|nh} x 3 passes ----
      f32x4 cR = {0,0,0,0}, cZ = {0,0,0,0}, cNI = {0,0,0,0}, cNH = {0,0,0,0};
#pragma unroll
      for (int ci=0; ci<3; ci++){
        const int c = 3*w8 + ci;
        const bf16x8 bhi = *(const bf16x8*)((char*)Uhi + jl*1552 + 64*c + 16*kq);
        const bf16x8 blo = *(const bf16x8*)((char*)Ulo + jl*1552 + 64*c + 16*kq);
        const bf16x8 aloR = *(const bf16x8*)(Wlo + ((size_t)(w8*9+3*ci+0)*64 + l)*16);
        const bf16x8 aloZ = *(const bf16x8*)(Wlo + ((size_t)(w8*9+3*ci+1)*64 + l)*16);
        const bf16x8 aloN = *(const bf16x8*)(Wlo + ((size_t)(w8*9+3*ci+2)*64 + l)*16);
        cR = MFMA(ahi[3*ci+0], bhi, cR);
        cR = MFMA(ahi[3*ci+0], blo, cR);
        cR = MFMA(aloR,        bhi, cR);
        cZ = MFMA(ahi[3*ci+1], bhi, cZ);
        cZ = MFMA(ahi[3*ci+1], blo, cZ);
        cZ = MFMA(aloZ,        bhi, cZ);
        if (c < 8){
          cNI = MFMA(ahi[3*ci+2], bhi, cNI);
          cNI = MFMA(ahi[3*ci+2], blo, cNI);
          cNI = MFMA(aloN,        bhi, cNI);
        } else {
          cNH = MFMA(ahi[3*ci+2], bhi, cNH);
          cNH = MFMA(ahi[3*ci+2], blo, cNH);
          cNH = MFMA(aloN,        bhi, cNH);
        }
      }
      // ---- cross-wave combine: ds_add_f32 into accb[4][16][17] ----
      {
        const int base = (kq*4)*17 + jl;
#pragma unroll
        for (int i=0;i<4;i++){
          atomicAdd(&accb[0*272 + base + i*17], cR[i]);
          atomicAdd(&accb[1*272 + base + i*17], cZ[i]);
        }
        if (w8 <= 2){
#pragma unroll
          for (int i=0;i<4;i++) atomicAdd(&accb[2*272 + base + i*17], cNI[i]);
        }
        if (w8 >= 2){
#pragma unroll
          for (int i=0;i<4;i++) atomicAdd(&accb[3*272 + base + i*17], cNH[i]);
        }
      }
      __syncthreads();                 // C: sums complete

      // ---- gates (256 threads): s = tid>>4, j = tid&15 ----
      if (tid < 256){
        const int s = tid>>4, j = tid&15;
        const float SR  = accb[0*272 + j*17 + s];
        const float SZ  = accb[1*272 + j*17 + s];
        const float SNI = accb[2*272 + j*17 + s];
        const float SNH = accb[3*272 + j*17 + s];
        const int hidx = 256 + w*JT + j;
        const float hold = __uint_as_float(((unsigned)Uhi[s*RWU + hidx])<<16)
                         + __uint_as_float(((unsigned)Ulo[s*RWU + hidx])<<16);
        const float r = sig_(SR + br);
        const float z = sig_(SZ + bz);
        const float n = tanh_(SNI + bni + r*(SNH + bnh));
        const float hnew = (1.0f - z)*n + z*hold;
        const unsigned short hh = bf16rn(hnew);
        const float fh = __uint_as_float(((unsigned)hh)<<16);
        const unsigned short ll2 = bf16rn(hnew - fh);
        const unsigned packed = (((unsigned)hh)<<16) | (unsigned)ll2;
        CSTOREU(hnx + (size_t)(b0+s)*H_ + w*JT + j, packed);
      }
      asm volatile("s_waitcnt vmcnt(0)" ::: "memory");
      __syncthreads();                 // D: hnew(g) drained wg-wide
      // ---- mailbox broadcast: lane c -> consumer c's (g) block, slot w ----
      if (tid < 32){
        int* fp = mbox + (tid*NGRP + g)*32 + w;
        const int fv = t + 1;
        CSTOREU(fp, fv);
      }
    }
  }
}

__global__ void head_k(const unsigned* __restrict__ h, const float* __restrict__ W_out,
                       const float* __restrict__ b_out, float* __restrict__ out)
{
  const int b = (int)blockIdx.x;       // 128 blocks, one sample each
  const int l = (int)threadIdx.x;      // 64 lanes
  const unsigned* hp = h + (size_t)b*H_ + l*8;
  const float* wp = W_out + l*8;
  float a = 0.f;
#pragma unroll
  for (int q=0;q<8;q++){
    const unsigned p = hp[q];
    const float v = __uint_as_float(p & 0xFFFF0000u) + __uint_as_float(p << 16);
    a = fmaf(v, wp[q], a);
  }
#pragma unroll
  for (int m=1;m<64;m<<=1) a += __shfl_xor(a, m, 64);
  if (l == 0) out[b] = sig_(a + b_out[0]);
}

extern "C" void kernel_launch(void* const* d_in, const int* in_sizes, int n_in,
                              void* d_out, int out_size, void* d_ws, size_t ws_size,
                              hipStream_t stream)
{
  const float* x    = (const float*)d_in[0];
  const float* Wih  = (const float*)d_in[1];
  const float* Whh  = (const float*)d_in[2];
  const float* bias = (const float*)d_in[3];
  const float* bn   = (const float*)d_in[4];
  const float* Wout = (const float*)d_in[5];
  const float* bout = (const float*)d_in[6];
  float* out      = (float*)d_out;
  unsigned* h_buf = (unsigned*)d_ws;                                        // 512 KB
  int* mbox       = (int*)((char*)d_ws + (size_t)2*B_*H_*sizeof(unsigned)); // 32 KB

  // zero h0 (packed 0 == 0.0f) + mailboxes every launch
  (void)hipMemsetAsync(d_ws, 0, (size_t)2*B_*H_*sizeof(unsigned)
                                 + (size_t)NWG*NGRP*32*4 + 4096, stream);

  (void)hipFuncSetAttribute((const void*)rnn_persist,
                            hipFuncAttributeMaxDynamicSharedMemorySize, LDS_DYN);

  void* args[7];
  args[0]=(void*)&x;    args[1]=(void*)&Wih;  args[2]=(void*)&Whh; args[3]=(void*)&bias;
  args[4]=(void*)&bn;   args[5]=(void*)&h_buf; args[6]=(void*)&mbox;
  hipError_t e = hipLaunchCooperativeKernel((const void*)rnn_persist,
                                            dim3(NWG), dim3(NT), args, LDS_DYN, stream);
  if (e != hipSuccess){
    (void)hipGetLastError();
    rnn_persist<<<dim3(NWG), dim3(NT), LDS_DYN, stream>>>(x, Wih, Whh, bias, bn, h_buf, mbox);
  }
  // T_ even -> final h in hb0; kernel boundary makes h_buf coherent for head_k
  head_k<<<dim3(128), dim3(64), 0, stream>>>(h_buf, Wout, bout, out);
}

// Round 20
// 12623.759 us; speedup vs baseline: 7.5586x; 7.5586x over previous
//
#include <hip/hip_runtime.h>

// GRU  B=128, T=1024, IN=256, H=512, OUT=1  (all fp32)
//
// v19 = v17 (passed, 11.49ms) + CACHED h-reads via agent-acquire fence.
// v18's decisive result: phases cost 11.6us even with polls pre-satisfied
// => the floor is the UNCACHED h-stage (2048 sc0sc1 dwordx4 requests/CU,
// latency-serialized at the CU's outstanding-miss slots), not exchange
// latency. Fix: producers keep sc0sc1 stores (visible at memory-side L3,
// proven v13/v17); consumer wave0, after poll success, performs ONE
// __hip_atomic_load(ACQUIRE, AGENT) -> compiler emits buffer_inv (L1+L2
// invalidate; the standard gfx94x agent-acquire, proven r1/r2); then the
// h-stage uses PLAIN CACHED dwordx4 loads: 64B-line coalescing -> ~512
// line-misses/CU (4x fewer), L3-resident data, L2 refill shared by
// same-XCD sibling wgs. Everything else v17-verbatim: mailbox flags
// (private 128B sectors), skewed stage, split-bf16 3-pass MFMA (A-hi VGPR,
// A-lo LDS), ds_add acc, tid<256 gates, packed (hi<<16|lo) h, sep head.

#define B_    128
#define T_    1024
#define IN_   256
#define H_    512
#define NG    8
#define WPG   32
#define SGRP  16
#define JT    16
#define NT    512
#define RWU   776                          // U row pitch (bf16 elems); *2B = 1552
#define U_HI_OFF   0
#define U_LO_OFF   (SGRP*RWU*2)            // 24,832
#define WLO_OFF    (2*SGRP*RWU*2)          // 49,664
#define ACC_OFF    (WLO_OFF + 8*9*64*16)   // 123,392
#define LDS_DYN    (ACC_OFF + 4*16*17*4)   // 127,744 B (also forces 1 wg/CU)

typedef __attribute__((ext_vector_type(8))) short bf16x8;
typedef __attribute__((ext_vector_type(4))) float f32x4;
union BCast { uint4 u; bf16x8 b; unsigned short s[8]; };

#define MFMA(a,b,c) __builtin_amdgcn_mfma_f32_16x16x32_bf16((a),(b),(c),0,0,0)

__device__ __forceinline__ float sig_(float v){ return 1.0f/(1.0f + __expf(-v)); }
__device__ __forceinline__ float tanh_(float v){
  float e = __expf(2.0f*v);
  return 1.0f - 2.0f/(e + 1.0f);
}
__device__ __forceinline__ unsigned short bf16rn(float f){
  unsigned u = __float_as_uint(f);
  return (unsigned short)((u + 0x7FFFu + ((u>>16)&1u)) >> 16);
}

// IF-coherent ops (sc0 sc1, proven v13/v17) -- producer/flag side only now.
#define CLOADI(dst, p)  asm volatile("global_load_dword %0, %1, off sc0 sc1"   : "=v"(dst) : "v"(p) : "memory")
#define CSTOREU(p, v)   asm volatile("global_store_dword %0, %1, off sc0 sc1"  :: "v"(p), "v"(v) : "memory")

// poll MY private 128B mailbox block (32 producer slots); v17-proven.
__device__ __forceinline__ int poll_mbox(const int* blk, int lane, int target){
  const int* fp = blk + (lane & 31);
  int guard = 0;
  for (;;){
    int fv;
    CLOADI(fv, fp);
    asm volatile("s_waitcnt vmcnt(0)" ::: "memory");
    if (__all(fv >= target)) return 0;
    __builtin_amdgcn_s_sleep(1);
    if (++guard > (1<<22)) return 1;
  }
}

__global__ void __launch_bounds__(NT, 2)
rnn_persist(const float* __restrict__ x, const float* __restrict__ W_ih,
            const float* __restrict__ W_hh, const float* __restrict__ bias,
            const float* __restrict__ bias_n, unsigned* __restrict__ h_buf,
            int* __restrict__ mbox)
{
  extern __shared__ char lds[];
  unsigned short* Uhi = (unsigned short*)(lds + U_HI_OFF);
  unsigned short* Ulo = (unsigned short*)(lds + U_LO_OFF);
  char*  Wlo  = lds + WLO_OFF;
  float* accb = (float*)(lds + ACC_OFF);

  const int bid = (int)blockIdx.x;
  const int g   = bid & (NG-1);
  const int w   = bid >> 3;
  const int tid = (int)threadIdx.x;
  const int w8  = tid >> 6;            // wave [0,8)
  const int l   = tid & 63;            // lane
  const int jl  = l & 15;              // frag row/col lane index
  const int kq  = l >> 4;              // k-quarter [0,4)
  const int b0  = g*SGRP;
  const int jg_l = w*JT + jl;
  const int lane = tid & 63;

  // ---- init: A-fragments. hi -> 36 VGPRs; lo -> LDS (frag-order) ----
  bf16x8 ahi[9];
#pragma unroll
  for (int ci=0; ci<3; ci++){
    const int c = 3*w8 + ci;
#pragma unroll
    for (int gi=0; gi<3; gi++){
      const int f = 3*ci + gi;
      const int grow = gi*H_ + jg_l;
      const float* p = (c < 8)
        ? (W_ih + (size_t)grow*IN_ + (32*c + 8*kq))
        : (W_hh + (size_t)grow*H_  + (32*c - 256 + 8*kq));
      const float4 v0 = *(const float4*)p;
      const float4 v1 = *(const float4*)(p+4);
      const float vv[8] = {v0.x,v0.y,v0.z,v0.w,v1.x,v1.y,v1.z,v1.w};
      BCast hi8, lo8;
#pragma unroll
      for (int i=0;i<8;i++){
        const unsigned short h = bf16rn(vv[i]);
        hi8.s[i] = h;
        lo8.s[i] = bf16rn(vv[i] - __uint_as_float(((unsigned)h)<<16));
      }
      ahi[f] = hi8.b;
      *(bf16x8*)(Wlo + ((size_t)(w8*9 + f)*64 + l)*16) = lo8.b;
    }
  }
  // biases for gate threads (j = tid&15)
  float br, bz, bni, bnh;
  { const int jj = w*JT + (tid & 15);
    br = bias[jj]; bz = bias[H_+jj]; bni = bias[2*H_+jj]; bnh = bias_n[jj]; }
  __syncthreads();                     // Wlo visible

  int* const mymbox = mbox + (g*WPG + w)*32;   // my private 128B flag block

  unsigned* const hb0 = h_buf;
  unsigned* const hb1 = h_buf + (size_t)B_*H_;
  int dead = 0;

  for (int t=0; t<T_; ++t){
    const unsigned* hc = (t & 1) ? hb1 : hb0;
    unsigned*      hnx = (t & 1) ? hb0 : hb1;

    // ---- zero acc buffer (prev gate phase ended at barrier D) ----
    for (int i=tid; i<4*16*17; i+=NT) accb[i] = 0.f;

    // ---- x-stage (flag-independent): fp32 -> bf16 hi/lo -> U[0:256) ----
    {
      const int ss = tid>>5, c2 = tid&31;
      const float* xp = x + ((size_t)(b0+ss)*T_ + (size_t)t)*IN_ + c2*8;
      const float4 a = *(const float4*)xp;
      const float4 b = *(const float4*)(xp+4);
      const float vv[8] = {a.x,a.y,a.z,a.w,b.x,b.y,b.z,b.w};
      unsigned hw[4], lw[4];
#pragma unroll
      for (int q=0;q<4;q++){
        const unsigned short h0 = bf16rn(vv[2*q]);
        const unsigned short h1 = bf16rn(vv[2*q+1]);
        const float f0 = __uint_as_float(((unsigned)h0)<<16);
        const float f1 = __uint_as_float(((unsigned)h1)<<16);
        const unsigned short l0 = bf16rn(vv[2*q]-f0);
        const unsigned short l1 = bf16rn(vv[2*q+1]-f1);
        hw[q] = (unsigned)h0 | ((unsigned)h1<<16);
        lw[q] = (unsigned)l0 | ((unsigned)l1<<16);
      }
      *(uint4*)((char*)Uhi + ss*1552 + c2*16) = make_uint4(hw[0],hw[1],hw[2],hw[3]);
      *(uint4*)((char*)Ulo + ss*1552 + c2*16) = make_uint4(lw[0],lw[1],lw[2],lw[3]);
    }

    // ---- wave0: poll my mailbox, then agent-acquire (buffer_inv L1+L2) ----
    if (tid < 64 && t > 0 && !dead){
      dead = poll_mbox(mymbox, lane, t);
      (void)__hip_atomic_load(mymbox, __ATOMIC_ACQUIRE, __HIP_MEMORY_SCOPE_AGENT);
    }
    __syncthreads();                   // P: h^t visible; caches invalidated

    // ---- h-stage (CACHED, skewed): plain dwordx4 loads -> split hi/lo ----
    {
      const int ss = ((tid>>5) + w) & 15;      // skewed sample
      const int c2 = ((tid&31) + w) & 31;      // skewed chunk
      const unsigned* hp = hc + (size_t)(b0+ss)*H_ + c2*16;
      const uint4 p0 = *(const uint4*)(hp);
      const uint4 p1 = *(const uint4*)(hp+4);
      const uint4 p2 = *(const uint4*)(hp+8);
      const uint4 p3 = *(const uint4*)(hp+12);
      const unsigned P[16] = {p0.x,p0.y,p0.z,p0.w, p1.x,p1.y,p1.z,p1.w,
                              p2.x,p2.y,p2.z,p2.w, p3.x,p3.y,p3.z,p3.w};
      unsigned hwv[8], lwv[8];
#pragma unroll
      for (int q=0;q<8;q++){
        hwv[q] = (P[2*q]>>16) | (P[2*q+1] & 0xFFFF0000u);
        lwv[q] = (P[2*q] & 0xFFFFu) | (P[2*q+1]<<16);
      }
      char* dh = (char*)Uhi + ss*1552 + 512 + c2*32;
      char* dl = (char*)Ulo + ss*1552 + 512 + c2*32;
      *(uint4*)dh      = make_uint4(hwv[0],hwv[1],hwv[2],hwv[3]);
      *(uint4*)(dh+16) = make_uint4(hwv[4],hwv[5],hwv[6],hwv[7]);
      *(uint4*)dl      = make_uint4(lwv[0],lwv[1],lwv[2],lwv[3]);
      *(uint4*)(dl+16) = make_uint4(lwv[4],lwv[5],lwv[6],lwv[7]);
    }
    __syncthreads();                   // B: U complete

    // ---- MFMA: 3 chunks x {r,z,ni|nh} x 3 passes ----
    f32x4 cR = {0,0,0,0}, cZ = {0,0,0,0}, cNI = {0,0,0,0}, cNH = {0,0,0,0};
#pragma unroll
    for (int ci=0; ci<3; ci++){
      const int c = 3*w8 + ci;
      const bf16x8 bhi = *(const bf16x8*)((char*)Uhi + jl*1552 + 64*c + 16*kq);
      const bf16x8 blo = *(const bf16x8*)((char*)Ulo + jl*1552 + 64*c + 16*kq);
      const bf16x8 aloR = *(const bf16x8*)(Wlo + ((size_t)(w8*9+3*ci+0)*64 + l)*16);
      const bf16x8 aloZ = *(const bf16x8*)(Wlo + ((size_t)(w8*9+3*ci+1)*64 + l)*16);
      const bf16x8 aloN = *(const bf16x8*)(Wlo + ((size_t)(w8*9+3*ci+2)*64 + l)*16);
      cR = MFMA(ahi[3*ci+0], bhi, cR);
      cR = MFMA(ahi[3*ci+0], blo, cR);
      cR = MFMA(aloR,        bhi, cR);
      cZ = MFMA(ahi[3*ci+1], bhi, cZ);
      cZ = MFMA(ahi[3*ci+1], blo, cZ);
      cZ = MFMA(aloZ,        bhi, cZ);
      if (c < 8){
        cNI = MFMA(ahi[3*ci+2], bhi, cNI);
        cNI = MFMA(ahi[3*ci+2], blo, cNI);
        cNI = MFMA(aloN,        bhi, cNI);
      } else {
        cNH = MFMA(ahi[3*ci+2], bhi, cNH);
        cNH = MFMA(ahi[3*ci+2], blo, cNH);
        cNH = MFMA(aloN,        bhi, cNH);
      }
    }
    // ---- cross-wave combine: ds_add_f32 into accb[4][16][17] ----
    {
      const int base = (kq*4)*17 + jl;
#pragma unroll
      for (int i=0;i<4;i++){
        atomicAdd(&accb[0*272 + base + i*17], cR[i]);
        atomicAdd(&accb[1*272 + base + i*17], cZ[i]);
      }
      if (w8 <= 2){
#pragma unroll
        for (int i=0;i<4;i++) atomicAdd(&accb[2*272 + base + i*17], cNI[i]);
      }
      if (w8 >= 2){
#pragma unroll
        for (int i=0;i<4;i++) atomicAdd(&accb[3*272 + base + i*17], cNH[i]);
      }
    }
    __syncthreads();                   // C: sums complete

    // ---- gates (256 threads): s = tid>>4, j = tid&15 ----
    if (tid < 256){
      const int s = tid>>4, j = tid&15;
      const float SR  = accb[0*272 + j*17 + s];
      const float SZ  = accb[1*272 + j*17 + s];
      const float SNI = accb[2*272 + j*17 + s];
      const float SNH = accb[3*272 + j*17 + s];
      const int hidx = 256 + w*JT + j;
      const float hold = __uint_as_float(((unsigned)Uhi[s*RWU + hidx])<<16)
                       + __uint_as_float(((unsigned)Ulo[s*RWU + hidx])<<16);
      const float r = sig_(SR + br);
      const float z = sig_(SZ + bz);
      const float n = tanh_(SNI + bni + r*(SNH + bnh));
      const float hnew = (1.0f - z)*n + z*hold;
      const unsigned short hh = bf16rn(hnew);
      const float fh = __uint_as_float(((unsigned)hh)<<16);
      const unsigned short ll2 = bf16rn(hnew - fh);
      const unsigned packed = (((unsigned)hh)<<16) | (unsigned)ll2;
      CSTOREU(hnx + (size_t)(b0+s)*H_ + w*JT + j, packed);
    }
    asm volatile("s_waitcnt vmcnt(0)" ::: "memory");
    __syncthreads();                   // D: all hnew stores drained
    // ---- mailbox broadcast: lane c -> consumer c's block, slot w ----
    if (tid < 32){
      int* fp = mbox + (g*WPG + tid)*32 + w;
      const int fv = t + 1;
      CSTOREU(fp, fv);
    }
  }
}

__global__ void head_k(const unsigned* __restrict__ h, const float* __restrict__ W_out,
                       const float* __restrict__ b_out, float* __restrict__ out)
{
  const int b = (int)blockIdx.x;       // 128 blocks, one sample each
  const int l = (int)threadIdx.x;      // 64 lanes
  const unsigned* hp = h + (size_t)b*H_ + l*8;
  const float* wp = W_out + l*8;
  float a = 0.f;
#pragma unroll
  for (int q=0;q<8;q++){
    const unsigned p = hp[q];
    const float v = __uint_as_float(p & 0xFFFF0000u) + __uint_as_float(p << 16);
    a = fmaf(v, wp[q], a);
  }
#pragma unroll
  for (int m=1;m<64;m<<=1) a += __shfl_xor(a, m, 64);
  if (l == 0) out[b] = sig_(a + b_out[0]);
}

extern "C" void kernel_launch(void* const* d_in, const int* in_sizes, int n_in,
                              void* d_out, int out_size, void* d_ws, size_t ws_size,
                              hipStream_t stream)
{
  const float* x    = (const float*)d_in[0];
  const float* Wih  = (const float*)d_in[1];
  const float* Whh  = (const float*)d_in[2];
  const float* bias = (const float*)d_in[3];
  const float* bn   = (const float*)d_in[4];
  const float* Wout = (const float*)d_in[5];
  const float* bout = (const float*)d_in[6];
  float* out      = (float*)d_out;
  unsigned* h_buf = (unsigned*)d_ws;                                     // 512 KB (2 bufs)
  int* mbox       = (int*)((char*)d_ws + (size_t)2*B_*H_*sizeof(unsigned)); // 32 KB

  // zero h0 (packed 0 == 0.0f) + mailboxes every launch
  (void)hipMemsetAsync(d_ws, 0, (size_t)2*B_*H_*sizeof(unsigned) + 8*WPG*32*4 + 4096, stream);

  (void)hipFuncSetAttribute((const void*)rnn_persist,
                            hipFuncAttributeMaxDynamicSharedMemorySize, LDS_DYN);

  void* args[7];
  args[0]=(void*)&x;    args[1]=(void*)&Wih;  args[2]=(void*)&Whh; args[3]=(void*)&bias;
  args[4]=(void*)&bn;   args[5]=(void*)&h_buf; args[6]=(void*)&mbox;
  hipError_t e = hipLaunchCooperativeKernel((const void*)rnn_persist,
                                            dim3(256), dim3(NT), args, LDS_DYN, stream);
  if (e != hipSuccess){
    (void)hipGetLastError();
    rnn_persist<<<dim3(256), dim3(NT), LDS_DYN, stream>>>(x, Wih, Whh, bias, bn, h_buf, mbox);
  }
  // T_ even -> final h in hb0; kernel boundary makes h_buf coherent for head_k
  head_k<<<dim3(128), dim3(64), 0, stream>>>(h_buf, Wout, bout, out);
}

// Round 21
// 4321.626 us; speedup vs baseline: 22.0791x; 2.9211x over previous
//
#include <hip/hip_runtime.h>

// GRU  B=128, T=1024, IN=256, H=512, OUT=1  (all fp32)
//
// v20 = v17 (best passing, 11.49ms) with the ds_add CROSS-WAVE REDUCTION
// replaced by contention-free slab writes + gate-phase summation.
// Rationale: v18 proved the phase BODY costs 11.6us with sync removed;
// v19 proved it's not the uncached h-load path alone (cached == uncached).
// The un-ablated suspect: ~7200 LDS atomic RMWs/wg/step (8 waves serializing
// on 1024 accumulator addresses) between barriers B and C. v20 ablates it:
//   slab[8 slots][4 gates][16 j][16 s] (32KB LDS, slot-major);
//   wave w8 writes its C-regs at slot = w8 ^ (jl&7) (bijective per bucket,
//   zero collisions, plain ds_write); NI (waves 0-2) / NH (waves 2-7)
//   unwritten slots zeroed ONCE before the t-loop; gate threads sum 8 slots.
//   Also removes the per-step acc zeroing (plain writes overwrite).
// Everything else v17-VERBATIM (sync/memory/compute untouched): mailbox
// flags (private 128B sectors), skewed sc0sc1 h-stage, split-bf16 3-pass
// MFMA (A-hi VGPR, A-lo LDS), tid<256 gates, packed (hi<<16|lo) h,
// separate head kernel.

#define B_    128
#define T_    1024
#define IN_   256
#define H_    512
#define NG    8
#define WPG   32
#define SGRP  16
#define JT    16
#define NT    512
#define RWU   776                          // U row pitch (bf16 elems); *2B = 1552
#define U_HI_OFF   0
#define U_LO_OFF   (SGRP*RWU*2)            // 24,832
#define WLO_OFF    (2*SGRP*RWU*2)          // 49,664
#define SLAB_OFF   (WLO_OFF + 8*9*64*16)   // 123,392
#define LDS_DYN    (SLAB_OFF + 8*1024*4)   // 156,160 B  (<= 160KB, 1 wg/CU)

typedef __attribute__((ext_vector_type(8))) short bf16x8;
typedef __attribute__((ext_vector_type(4))) float f32x4;
union BCast { uint4 u; bf16x8 b; unsigned short s[8]; };

#define MFMA(a,b,c) __builtin_amdgcn_mfma_f32_16x16x32_bf16((a),(b),(c),0,0,0)

__device__ __forceinline__ float sig_(float v){ return 1.0f/(1.0f + __expf(-v)); }
__device__ __forceinline__ float tanh_(float v){
  float e = __expf(2.0f*v);
  return 1.0f - 2.0f/(e + 1.0f);
}
__device__ __forceinline__ unsigned short bf16rn(float f){
  unsigned u = __float_as_uint(f);
  return (unsigned short)((u + 0x7FFFu + ((u>>16)&1u)) >> 16);
}

// IF-coherent ops (sc0 sc1, proven v13/v17).
#define CLOADU4(dst, p) asm volatile("global_load_dwordx4 %0, %1, off sc0 sc1" : "=v"(dst) : "v"(p) : "memory")
#define CLOADI(dst, p)  asm volatile("global_load_dword %0, %1, off sc0 sc1"   : "=v"(dst) : "v"(p) : "memory")
#define CSTOREU(p, v)   asm volatile("global_store_dword %0, %1, off sc0 sc1"  :: "v"(p), "v"(v) : "memory")
#define VWAIT0()        do{ asm volatile("s_waitcnt vmcnt(0)" ::: "memory"); __builtin_amdgcn_sched_barrier(0); }while(0)

// poll MY private 128B mailbox block (32 producer slots); v17-proven.
__device__ __forceinline__ int poll_mbox(const int* blk, int lane, int target){
  const int* fp = blk + (lane & 31);
  int guard = 0;
  for (;;){
    int fv;
    CLOADI(fv, fp);
    asm volatile("s_waitcnt vmcnt(0)" ::: "memory");
    if (__all(fv >= target)) return 0;
    __builtin_amdgcn_s_sleep(1);
    if (++guard > (1<<22)) return 1;
  }
}

__global__ void __launch_bounds__(NT, 2)
rnn_persist(const float* __restrict__ x, const float* __restrict__ W_ih,
            const float* __restrict__ W_hh, const float* __restrict__ bias,
            const float* __restrict__ bias_n, unsigned* __restrict__ h_buf,
            int* __restrict__ mbox)
{
  extern __shared__ char lds[];
  unsigned short* Uhi = (unsigned short*)(lds + U_HI_OFF);
  unsigned short* Ulo = (unsigned short*)(lds + U_LO_OFF);
  char*  Wlo  = lds + WLO_OFF;
  float* slab = (float*)(lds + SLAB_OFF);   // [slot 0..7][gate 0..3][j][s]

  const int bid = (int)blockIdx.x;
  const int g   = bid & (NG-1);
  const int w   = bid >> 3;
  const int tid = (int)threadIdx.x;
  const int w8  = tid >> 6;            // wave [0,8)
  const int l   = tid & 63;            // lane
  const int jl  = l & 15;              // frag row/col lane index
  const int kq  = l >> 4;              // k-quarter [0,4)
  const int b0  = g*SGRP;
  const int jg_l = w*JT + jl;
  const int lane = tid & 63;

  // ---- init: A-fragments. hi -> 36 VGPRs; lo -> LDS (frag-order) ----
  bf16x8 ahi[9];
#pragma unroll
  for (int ci=0; ci<3; ci++){
    const int c = 3*w8 + ci;
#pragma unroll
    for (int gi=0; gi<3; gi++){
      const int f = 3*ci + gi;
      const int grow = gi*H_ + jg_l;
      const float* p = (c < 8)
        ? (W_ih + (size_t)grow*IN_ + (32*c + 8*kq))
        : (W_hh + (size_t)grow*H_  + (32*c - 256 + 8*kq));
      const float4 v0 = *(const float4*)p;
      const float4 v1 = *(const float4*)(p+4);
      const float vv[8] = {v0.x,v0.y,v0.z,v0.w,v1.x,v1.y,v1.z,v1.w};
      BCast hi8, lo8;
#pragma unroll
      for (int i=0;i<8;i++){
        const unsigned short h = bf16rn(vv[i]);
        hi8.s[i] = h;
        lo8.s[i] = bf16rn(vv[i] - __uint_as_float(((unsigned)h)<<16));
      }
      ahi[f] = hi8.b;
      *(bf16x8*)(Wlo + ((size_t)(w8*9 + f)*64 + l)*16) = lo8.b;
    }
  }
  // biases for gate threads (j = tid&15)
  float br, bz, bni, bnh;
  { const int jj = w*JT + (tid & 15);
    br = bias[jj]; bz = bias[H_+jj]; bni = bias[2*H_+jj]; bnh = bias_n[jj]; }
  // zero the whole slab ONCE (unwritten NI/NH slots must read as 0 forever)
  for (int i=tid; i<8*1024; i+=NT) slab[i] = 0.f;
  __syncthreads();                     // Wlo + slab visible

  int* const mymbox = mbox + (g*WPG + w)*32;   // my private 128B flag block

  unsigned* const hb0 = h_buf;
  unsigned* const hb1 = h_buf + (size_t)B_*H_;
  int dead = 0;
  const int myslot = w8 ^ (jl & 7);    // per-bucket bijective slot (b&7 == jl&7)

  for (int t=0; t<T_; ++t){
    const unsigned* hc = (t & 1) ? hb1 : hb0;
    unsigned*      hnx = (t & 1) ? hb0 : hb1;

    // ---- x-stage (flag-independent): fp32 -> bf16 hi/lo -> U[0:256) ----
    {
      const int ss = tid>>5, c2 = tid&31;
      const float* xp = x + ((size_t)(b0+ss)*T_ + (size_t)t)*IN_ + c2*8;
      const float4 a = *(const float4*)xp;
      const float4 b = *(const float4*)(xp+4);
      const float vv[8] = {a.x,a.y,a.z,a.w,b.x,b.y,b.z,b.w};
      unsigned hw[4], lw[4];
#pragma unroll
      for (int q=0;q<4;q++){
        const unsigned short h0 = bf16rn(vv[2*q]);
        const unsigned short h1 = bf16rn(vv[2*q+1]);
        const float f0 = __uint_as_float(((unsigned)h0)<<16);
        const float f1 = __uint_as_float(((unsigned)h1)<<16);
        const unsigned short l0 = bf16rn(vv[2*q]-f0);
        const unsigned short l1 = bf16rn(vv[2*q+1]-f1);
        hw[q] = (unsigned)h0 | ((unsigned)h1<<16);
        lw[q] = (unsigned)l0 | ((unsigned)l1<<16);
      }
      *(uint4*)((char*)Uhi + ss*1552 + c2*16) = make_uint4(hw[0],hw[1],hw[2],hw[3]);
      *(uint4*)((char*)Ulo + ss*1552 + c2*16) = make_uint4(lw[0],lw[1],lw[2],lw[3]);
    }

    // ---- wave0 polls MY private mailbox; others wait at barrier P ----
    if (tid < 64 && t > 0 && !dead) dead = poll_mbox(mymbox, lane, t);
    __syncthreads();                   // P: h^t globally visible

    // ---- h-stage (SKEWED): packed u32 -> split hi/lo -> U[256:768) ----
    {
      const int ss = ((tid>>5) + w) & 15;      // skewed sample
      const int c2 = ((tid&31) + w) & 31;      // skewed chunk
      const unsigned* hp = hc + (size_t)(b0+ss)*H_ + c2*16;
      uint4 p0,p1,p2,p3;
      CLOADU4(p0, hp); CLOADU4(p1, hp+4); CLOADU4(p2, hp+8); CLOADU4(p3, hp+12);
      VWAIT0();
      const unsigned P[16] = {p0.x,p0.y,p0.z,p0.w, p1.x,p1.y,p1.z,p1.w,
                              p2.x,p2.y,p2.z,p2.w, p3.x,p3.y,p3.z,p3.w};
      unsigned hwv[8], lwv[8];
#pragma unroll
      for (int q=0;q<8;q++){
        hwv[q] = (P[2*q]>>16) | (P[2*q+1] & 0xFFFF0000u);
        lwv[q] = (P[2*q] & 0xFFFFu) | (P[2*q+1]<<16);
      }
      char* dh = (char*)Uhi + ss*1552 + 512 + c2*32;
      char* dl = (char*)Ulo + ss*1552 + 512 + c2*32;
      *(uint4*)dh      = make_uint4(hwv[0],hwv[1],hwv[2],hwv[3]);
      *(uint4*)(dh+16) = make_uint4(hwv[4],hwv[5],hwv[6],hwv[7]);
      *(uint4*)dl      = make_uint4(lwv[0],lwv[1],lwv[2],lwv[3]);
      *(uint4*)(dl+16) = make_uint4(lwv[4],lwv[5],lwv[6],lwv[7]);
    }
    __syncthreads();                   // B: U complete

    // ---- MFMA: 3 chunks x {r,z,ni|nh} x 3 passes ----
    f32x4 cR = {0,0,0,0}, cZ = {0,0,0,0}, cNI = {0,0,0,0}, cNH = {0,0,0,0};
#pragma unroll
    for (int ci=0; ci<3; ci++){
      const int c = 3*w8 + ci;
      const bf16x8 bhi = *(const bf16x8*)((char*)Uhi + jl*1552 + 64*c + 16*kq);
      const bf16x8 blo = *(const bf16x8*)((char*)Ulo + jl*1552 + 64*c + 16*kq);
      const bf16x8 aloR = *(const bf16x8*)(Wlo + ((size_t)(w8*9+3*ci+0)*64 + l)*16);
      const bf16x8 aloZ = *(const bf16x8*)(Wlo + ((size_t)(w8*9+3*ci+1)*64 + l)*16);
      const bf16x8 aloN = *(const bf16x8*)(Wlo + ((size_t)(w8*9+3*ci+2)*64 + l)*16);
      cR = MFMA(ahi[3*ci+0], bhi, cR);
      cR = MFMA(ahi[3*ci+0], blo, cR);
      cR = MFMA(aloR,        bhi, cR);
      cZ = MFMA(ahi[3*ci+1], bhi, cZ);
      cZ = MFMA(ahi[3*ci+1], blo, cZ);
      cZ = MFMA(aloZ,        bhi, cZ);
      if (c < 8){
        cNI = MFMA(ahi[3*ci+2], bhi, cNI);
        cNI = MFMA(ahi[3*ci+2], blo, cNI);
        cNI = MFMA(aloN,        bhi, cNI);
      } else {
        cNH = MFMA(ahi[3*ci+2], bhi, cNH);
        cNH = MFMA(ahi[3*ci+2], blo, cNH);
        cNH = MFMA(aloN,        bhi, cNH);
      }
    }
    // ---- cross-wave combine: CONTENTION-FREE slab writes (no atomics) ----
    // bucket b = j_out*16 + s = (4kq+i)*16 + jl; addr = myslot*1024 + G*256 + b
    {
      float* sb = slab + myslot*1024;
#pragma unroll
      for (int i=0;i<4;i++){
        const int b = (4*kq+i)*16 + jl;
        sb[0*256 + b] = cR[i];
        sb[1*256 + b] = cZ[i];
      }
      if (w8 <= 2){
#pragma unroll
        for (int i=0;i<4;i++) sb[2*256 + (4*kq+i)*16 + jl] = cNI[i];
      }
      if (w8 >= 2){
#pragma unroll
        for (int i=0;i<4;i++) sb[3*256 + (4*kq+i)*16 + jl] = cNH[i];
      }
    }
    __syncthreads();                   // C: slab complete

    // ---- gates (256 threads): s = tid>>4, j = tid&15; sum 8 slots ----
    if (tid < 256){
      const int s = tid>>4, j = tid&15;
      const int b = j*16 + s;
      float SR=0.f, SZ=0.f, SNI=0.f, SNH=0.f;
#pragma unroll
      for (int sl=0; sl<8; sl++){
        const float* sb = slab + sl*1024;
        SR  += sb[0*256 + b];
        SZ  += sb[1*256 + b];
        SNI += sb[2*256 + b];
        SNH += sb[3*256 + b];
      }
      const int hidx = 256 + w*JT + j;
      const float hold = __uint_as_float(((unsigned)Uhi[s*RWU + hidx])<<16)
                       + __uint_as_float(((unsigned)Ulo[s*RWU + hidx])<<16);
      const float r = sig_(SR + br);
      const float z = sig_(SZ + bz);
      const float n = tanh_(SNI + bni + r*(SNH + bnh));
      const float hnew = (1.0f - z)*n + z*hold;
      const unsigned short hh = bf16rn(hnew);
      const float fh = __uint_as_float(((unsigned)hh)<<16);
      const unsigned short ll2 = bf16rn(hnew - fh);
      const unsigned packed = (((unsigned)hh)<<16) | (unsigned)ll2;
      CSTOREU(hnx + (size_t)(b0+s)*H_ + w*JT + j, packed);
    }
    asm volatile("s_waitcnt vmcnt(0)" ::: "memory");
    __syncthreads();                   // D: all hnew stores drained
    // ---- mailbox broadcast: lane c -> consumer c's block, slot w ----
    if (tid < 32){
      int* fp = mbox + (g*WPG + tid)*32 + w;
      const int fv = t + 1;
      CSTOREU(fp, fv);
    }
  }
}

__global__ void head_k(const unsigned* __restrict__ h, const float* __restrict__ W_out,
                       const float* __restrict__ b_out, float* __restrict__ out)
{
  const int b = (int)blockIdx.x;       // 128 blocks, one sample each
  const int l = (int)threadIdx.x;      // 64 lanes
  const unsigned* hp = h + (size_t)b*H_ + l*8;
  const float* wp = W_out + l*8;
  float a = 0.f;
#pragma unroll
  for (int q=0;q<8;q++){
    const unsigned p = hp[q];
    const float v = __uint_as_float(p & 0xFFFF0000u) + __uint_as_float(p << 16);
    a = fmaf(v, wp[q], a);
  }
#pragma unroll
  for (int m=1;m<64;m<<=1) a += __shfl_xor(a, m, 64);
  if (l == 0) out[b] = sig_(a + b_out[0]);
}

extern "C" void kernel_launch(void* const* d_in, const int* in_sizes, int n_in,
                              void* d_out, int out_size, void* d_ws, size_t ws_size,
                              hipStream_t stream)
{
  const float* x    = (const float*)d_in[0];
  const float* Wih  = (const float*)d_in[1];
  const float* Whh  = (const float*)d_in[2];
  const float* bias = (const float*)d_in[3];
  const float* bn   = (const float*)d_in[4];
  const float* Wout = (const float*)d_in[5];
  const float* bout = (const float*)d_in[6];
  float* out      = (float*)d_out;
  unsigned* h_buf = (unsigned*)d_ws;                                     // 512 KB (2 bufs)
  int* mbox       = (int*)((char*)d_ws + (size_t)2*B_*H_*sizeof(unsigned)); // 32 KB

  // zero h0 (packed 0 == 0.0f) + mailboxes every launch
  (void)hipMemsetAsync(d_ws, 0, (size_t)2*B_*H_*sizeof(unsigned) + 8*WPG*32*4 + 4096, stream);

  (void)hipFuncSetAttribute((const void*)rnn_persist,
                            hipFuncAttributeMaxDynamicSharedMemorySize, LDS_DYN);

  void* args[7];
  args[0]=(void*)&x;    args[1]=(void*)&Wih;  args[2]=(void*)&Whh; args[3]=(void*)&bias;
  args[4]=(void*)&bn;   args[5]=(void*)&h_buf; args[6]=(void*)&mbox;
  hipError_t e = hipLaunchCooperativeKernel((const void*)rnn_persist,
                                            dim3(256), dim3(NT), args, LDS_DYN, stream);
  if (e != hipSuccess){
    (void)hipGetLastError();
    rnn_persist<<<dim3(256), dim3(NT), LDS_DYN, stream>>>(x, Wih, Whh, bias, bn, h_buf, mbox);
  }
  // T_ even -> final h in hb0; kernel boundary makes h_buf coherent for head_k
  head_k<<<dim3(128), dim3(64), 0, stream>>>(h_buf, Wout, bout, out);
}

// Round 22
// 3637.980 us; speedup vs baseline: 26.2282x; 1.1879x over previous
//
#include <hip/hip_runtime.h>

// GRU  B=128, T=1024, IN=256, H=512, OUT=1  (all fp32)
//
// v21 = v20 (passed, 4.32ms -- the ds_add removal was a 2.7x win) with the
// slab re-strided for ~2-way (free) bank access on BOTH sides:
//   v20 layout: bucket=j*16+s -> writes 4-way (kq collide), gate reads 8-way
//   (8 lanes/bank) => +5.1e8 conflict cycles = ~0.78us/step.
//   v21 strides: j-stride 18, gate-stride 292, slot-stride 1184:
//     write bank = (8kq + 18i + jl) mod 32  -> exactly 2 lanes/bank
//     read  bank = (18j + s) mod 32         -> <=2 lanes/bank
//   slot = w8 (plain; stride does the spreading). LDS = 161,280B (<=160KiB).
// Everything else v20-VERBATIM: mailbox flags (private 128B sectors), skewed
// sc0sc1 h-stage, split-bf16 3-pass MFMA (A-hi VGPR, A-lo LDS), slab writes
// + gate-phase sum (no atomics), tid<256 gates, packed (hi<<16|lo) h,
// separate head kernel.

#define B_    128
#define T_    1024
#define IN_   256
#define H_    512
#define NG    8
#define WPG   32
#define SGRP  16
#define JT    16
#define NT    512
#define RWU   776                          // U row pitch (bf16 elems); *2B = 1552
#define U_HI_OFF   0
#define U_LO_OFF   (SGRP*RWU*2)            // 24,832
#define WLO_OFF    (2*SGRP*RWU*2)          // 49,664
#define SLAB_OFF   (WLO_OFF + 8*9*64*16)   // 123,392
#define SJ    18                           // slab j-stride (floats)
#define SGT   292                          // slab gate-stride (>=16*18)
#define SSL   1184                         // slab slot-stride (>=4*292)
#define LDS_DYN    (SLAB_OFF + 8*SSL*4)    // 161,280 B (<= 163,840; 1 wg/CU)

typedef __attribute__((ext_vector_type(8))) short bf16x8;
typedef __attribute__((ext_vector_type(4))) float f32x4;
union BCast { uint4 u; bf16x8 b; unsigned short s[8]; };

#define MFMA(a,b,c) __builtin_amdgcn_mfma_f32_16x16x32_bf16((a),(b),(c),0,0,0)

__device__ __forceinline__ float sig_(float v){ return 1.0f/(1.0f + __expf(-v)); }
__device__ __forceinline__ float tanh_(float v){
  float e = __expf(2.0f*v);
  return 1.0f - 2.0f/(e + 1.0f);
}
__device__ __forceinline__ unsigned short bf16rn(float f){
  unsigned u = __float_as_uint(f);
  return (unsigned short)((u + 0x7FFFu + ((u>>16)&1u)) >> 16);
}

// IF-coherent ops (sc0 sc1, proven v13/v17/v20).
#define CLOADU4(dst, p) asm volatile("global_load_dwordx4 %0, %1, off sc0 sc1" : "=v"(dst) : "v"(p) : "memory")
#define CLOADI(dst, p)  asm volatile("global_load_dword %0, %1, off sc0 sc1"   : "=v"(dst) : "v"(p) : "memory")
#define CSTOREU(p, v)   asm volatile("global_store_dword %0, %1, off sc0 sc1"  :: "v"(p), "v"(v) : "memory")
#define VWAIT0()        do{ asm volatile("s_waitcnt vmcnt(0)" ::: "memory"); __builtin_amdgcn_sched_barrier(0); }while(0)

// poll MY private 128B mailbox block (32 producer slots); v17-proven.
__device__ __forceinline__ int poll_mbox(const int* blk, int lane, int target){
  const int* fp = blk + (lane & 31);
  int guard = 0;
  for (;;){
    int fv;
    CLOADI(fv, fp);
    asm volatile("s_waitcnt vmcnt(0)" ::: "memory");
    if (__all(fv >= target)) return 0;
    __builtin_amdgcn_s_sleep(1);
    if (++guard > (1<<22)) return 1;
  }
}

__global__ void __launch_bounds__(NT, 2)
rnn_persist(const float* __restrict__ x, const float* __restrict__ W_ih,
            const float* __restrict__ W_hh, const float* __restrict__ bias,
            const float* __restrict__ bias_n, unsigned* __restrict__ h_buf,
            int* __restrict__ mbox)
{
  extern __shared__ char lds[];
  unsigned short* Uhi = (unsigned short*)(lds + U_HI_OFF);
  unsigned short* Ulo = (unsigned short*)(lds + U_LO_OFF);
  char*  Wlo  = lds + WLO_OFF;
  float* slab = (float*)(lds + SLAB_OFF);   // [slot][gate][j(SJ)][s]

  const int bid = (int)blockIdx.x;
  const int g   = bid & (NG-1);
  const int w   = bid >> 3;
  const int tid = (int)threadIdx.x;
  const int w8  = tid >> 6;            // wave [0,8)
  const int l   = tid & 63;            // lane
  const int jl  = l & 15;              // frag row/col lane index
  const int kq  = l >> 4;              // k-quarter [0,4)
  const int b0  = g*SGRP;
  const int jg_l = w*JT + jl;
  const int lane = tid & 63;

  // ---- init: A-fragments. hi -> 36 VGPRs; lo -> LDS (frag-order) ----
  bf16x8 ahi[9];
#pragma unroll
  for (int ci=0; ci<3; ci++){
    const int c = 3*w8 + ci;
#pragma unroll
    for (int gi=0; gi<3; gi++){
      const int f = 3*ci + gi;
      const int grow = gi*H_ + jg_l;
      const float* p = (c < 8)
        ? (W_ih + (size_t)grow*IN_ + (32*c + 8*kq))
        : (W_hh + (size_t)grow*H_  + (32*c - 256 + 8*kq));
      const float4 v0 = *(const float4*)p;
      const float4 v1 = *(const float4*)(p+4);
      const float vv[8] = {v0.x,v0.y,v0.z,v0.w,v1.x,v1.y,v1.z,v1.w};
      BCast hi8, lo8;
#pragma unroll
      for (int i=0;i<8;i++){
        const unsigned short h = bf16rn(vv[i]);
        hi8.s[i] = h;
        lo8.s[i] = bf16rn(vv[i] - __uint_as_float(((unsigned)h)<<16));
      }
      ahi[f] = hi8.b;
      *(bf16x8*)(Wlo + ((size_t)(w8*9 + f)*64 + l)*16) = lo8.b;
    }
  }
  // biases for gate threads (j = tid&15)
  float br, bz, bni, bnh;
  { const int jj = w*JT + (tid & 15);
    br = bias[jj]; bz = bias[H_+jj]; bni = bias[2*H_+jj]; bnh = bias_n[jj]; }
  // zero the whole slab ONCE (unwritten NI/NH slots must read as 0 forever)
  for (int i=tid; i<8*SSL; i+=NT) slab[i] = 0.f;
  __syncthreads();                     // Wlo + slab visible

  int* const mymbox = mbox + (g*WPG + w)*32;   // my private 128B flag block

  unsigned* const hb0 = h_buf;
  unsigned* const hb1 = h_buf + (size_t)B_*H_;
  int dead = 0;

  for (int t=0; t<T_; ++t){
    const unsigned* hc = (t & 1) ? hb1 : hb0;
    unsigned*      hnx = (t & 1) ? hb0 : hb1;

    // ---- x-stage (flag-independent): fp32 -> bf16 hi/lo -> U[0:256) ----
    {
      const int ss = tid>>5, c2 = tid&31;
      const float* xp = x + ((size_t)(b0+ss)*T_ + (size_t)t)*IN_ + c2*8;
      const float4 a = *(const float4*)xp;
      const float4 b = *(const float4*)(xp+4);
      const float vv[8] = {a.x,a.y,a.z,a.w,b.x,b.y,b.z,b.w};
      unsigned hw[4], lw[4];
#pragma unroll
      for (int q=0;q<4;q++){
        const unsigned short h0 = bf16rn(vv[2*q]);
        const unsigned short h1 = bf16rn(vv[2*q+1]);
        const float f0 = __uint_as_float(((unsigned)h0)<<16);
        const float f1 = __uint_as_float(((unsigned)h1)<<16);
        const unsigned short l0 = bf16rn(vv[2*q]-f0);
        const unsigned short l1 = bf16rn(vv[2*q+1]-f1);
        hw[q] = (unsigned)h0 | ((unsigned)h1<<16);
        lw[q] = (unsigned)l0 | ((unsigned)l1<<16);
      }
      *(uint4*)((char*)Uhi + ss*1552 + c2*16) = make_uint4(hw[0],hw[1],hw[2],hw[3]);
      *(uint4*)((char*)Ulo + ss*1552 + c2*16) = make_uint4(lw[0],lw[1],lw[2],lw[3]);
    }

    // ---- wave0 polls MY private mailbox; others wait at barrier P ----
    if (tid < 64 && t > 0 && !dead) dead = poll_mbox(mymbox, lane, t);
    __syncthreads();                   // P: h^t globally visible

    // ---- h-stage (SKEWED): packed u32 -> split hi/lo -> U[256:768) ----
    {
      const int ss = ((tid>>5) + w) & 15;      // skewed sample
      const int c2 = ((tid&31) + w) & 31;      // skewed chunk
      const unsigned* hp = hc + (size_t)(b0+ss)*H_ + c2*16;
      uint4 p0,p1,p2,p3;
      CLOADU4(p0, hp); CLOADU4(p1, hp+4); CLOADU4(p2, hp+8); CLOADU4(p3, hp+12);
      VWAIT0();
      const unsigned P[16] = {p0.x,p0.y,p0.z,p0.w, p1.x,p1.y,p1.z,p1.w,
                              p2.x,p2.y,p2.z,p2.w, p3.x,p3.y,p3.z,p3.w};
      unsigned hwv[8], lwv[8];
#pragma unroll
      for (int q=0;q<8;q++){
        hwv[q] = (P[2*q]>>16) | (P[2*q+1] & 0xFFFF0000u);
        lwv[q] = (P[2*q] & 0xFFFFu) | (P[2*q+1]<<16);
      }
      char* dh = (char*)Uhi + ss*1552 + 512 + c2*32;
      char* dl = (char*)Ulo + ss*1552 + 512 + c2*32;
      *(uint4*)dh      = make_uint4(hwv[0],hwv[1],hwv[2],hwv[3]);
      *(uint4*)(dh+16) = make_uint4(hwv[4],hwv[5],hwv[6],hwv[7]);
      *(uint4*)dl      = make_uint4(lwv[0],lwv[1],lwv[2],lwv[3]);
      *(uint4*)(dl+16) = make_uint4(lwv[4],lwv[5],lwv[6],lwv[7]);
    }
    __syncthreads();                   // B: U complete

    // ---- MFMA: 3 chunks x {r,z,ni|nh} x 3 passes ----
    f32x4 cR = {0,0,0,0}, cZ = {0,0,0,0}, cNI = {0,0,0,0}, cNH = {0,0,0,0};
#pragma unroll
    for (int ci=0; ci<3; ci++){
      const int c = 3*w8 + ci;
      const bf16x8 bhi = *(const bf16x8*)((char*)Uhi + jl*1552 + 64*c + 16*kq);
      const bf16x8 blo = *(const bf16x8*)((char*)Ulo + jl*1552 + 64*c + 16*kq);
      const bf16x8 aloR = *(const bf16x8*)(Wlo + ((size_t)(w8*9+3*ci+0)*64 + l)*16);
      const bf16x8 aloZ = *(const bf16x8*)(Wlo + ((size_t)(w8*9+3*ci+1)*64 + l)*16);
      const bf16x8 aloN = *(const bf16x8*)(Wlo + ((size_t)(w8*9+3*ci+2)*64 + l)*16);
      cR = MFMA(ahi[3*ci+0], bhi, cR);
      cR = MFMA(ahi[3*ci+0], blo, cR);
      cR = MFMA(aloR,        bhi, cR);
      cZ = MFMA(ahi[3*ci+1], bhi, cZ);
      cZ = MFMA(ahi[3*ci+1], blo, cZ);
      cZ = MFMA(aloZ,        bhi, cZ);
      if (c < 8){
        cNI = MFMA(ahi[3*ci+2], bhi, cNI);
        cNI = MFMA(ahi[3*ci+2], blo, cNI);
        cNI = MFMA(aloN,        bhi, cNI);
      } else {
        cNH = MFMA(ahi[3*ci+2], bhi, cNH);
        cNH = MFMA(ahi[3*ci+2], blo, cNH);
        cNH = MFMA(aloN,        bhi, cNH);
      }
    }
    // ---- cross-wave combine: contention-free slab writes, 2-way banks ----
    // write addr = w8*SSL + gate*SGT + j_out*SJ + s;  j_out = 4kq+i, s = jl
    {
      float* sb = slab + w8*SSL;
#pragma unroll
      for (int i=0;i<4;i++){
        const int o = (4*kq+i)*SJ + jl;
        sb[0*SGT + o] = cR[i];
        sb[1*SGT + o] = cZ[i];
      }
      if (w8 <= 2){
#pragma unroll
        for (int i=0;i<4;i++) sb[2*SGT + (4*kq+i)*SJ + jl] = cNI[i];
      }
      if (w8 >= 2){
#pragma unroll
        for (int i=0;i<4;i++) sb[3*SGT + (4*kq+i)*SJ + jl] = cNH[i];
      }
    }
    __syncthreads();                   // C: slab complete

    // ---- gates (256 threads): s = tid>>4, j = tid&15; sum 8 slots ----
    if (tid < 256){
      const int s = tid>>4, j = tid&15;
      const int o = j*SJ + s;
      float SR=0.f, SZ=0.f, SNI=0.f, SNH=0.f;
#pragma unroll
      for (int sl=0; sl<8; sl++){
        const float* sb = slab + sl*SSL;
        SR  += sb[0*SGT + o];
        SZ  += sb[1*SGT + o];
        SNI += sb[2*SGT + o];
        SNH += sb[3*SGT + o];
      }
      const int hidx = 256 + w*JT + j;
      const float hold = __uint_as_float(((unsigned)Uhi[s*RWU + hidx])<<16)
                       + __uint_as_float(((unsigned)Ulo[s*RWU + hidx])<<16);
      const float r = sig_(SR + br);
      const float z = sig_(SZ + bz);
      const float n = tanh_(SNI + bni + r*(SNH + bnh));
      const float hnew = (1.0f - z)*n + z*hold;
      const unsigned short hh = bf16rn(hnew);
      const float fh = __uint_as_float(((unsigned)hh)<<16);
      const unsigned short ll2 = bf16rn(hnew - fh);
      const unsigned packed = (((unsigned)hh)<<16) | (unsigned)ll2;
      CSTOREU(hnx + (size_t)(b0+s)*H_ + w*JT + j, packed);
    }
    asm volatile("s_waitcnt vmcnt(0)" ::: "memory");
    __syncthreads();                   // D: all hnew stores drained
    // ---- mailbox broadcast: lane c -> consumer c's block, slot w ----
    if (tid < 32){
      int* fp = mbox + (g*WPG + tid)*32 + w;
      const int fv = t + 1;
      CSTOREU(fp, fv);
    }
  }
}

__global__ void head_k(const unsigned* __restrict__ h, const float* __restrict__ W_out,
                       const float* __restrict__ b_out, float* __restrict__ out)
{
  const int b = (int)blockIdx.x;       // 128 blocks, one sample each
  const int l = (int)threadIdx.x;      // 64 lanes
  const unsigned* hp = h + (size_t)b*H_ + l*8;
  const float* wp = W_out + l*8;
  float a = 0.f;
#pragma unroll
  for (int q=0;q<8;q++){
    const unsigned p = hp[q];
    const float v = __uint_as_float(p & 0xFFFF0000u) + __uint_as_float(p << 16);
    a = fmaf(v, wp[q], a);
  }
#pragma unroll
  for (int m=1;m<64;m<<=1) a += __shfl_xor(a, m, 64);
  if (l == 0) out[b] = sig_(a + b_out[0]);
}

extern "C" void kernel_launch(void* const* d_in, const int* in_sizes, int n_in,
                              void* d_out, int out_size, void* d_ws, size_t ws_size,
                              hipStream_t stream)
{
  const float* x    = (const float*)d_in[0];
  const float* Wih  = (const float*)d_in[1];
  const float* Whh  = (const float*)d_in[2];
  const float* bias = (const float*)d_in[3];
  const float* bn   = (const float*)d_in[4];
  const float* Wout = (const float*)d_in[5];
  const float* bout = (const float*)d_in[6];
  float* out      = (float*)d_out;
  unsigned* h_buf = (unsigned*)d_ws;                                     // 512 KB (2 bufs)
  int* mbox       = (int*)((char*)d_ws + (size_t)2*B_*H_*sizeof(unsigned)); // 32 KB

  // zero h0 (packed 0 == 0.0f) + mailboxes every launch
  (void)hipMemsetAsync(d_ws, 0, (size_t)2*B_*H_*sizeof(unsigned) + 8*WPG*32*4 + 4096, stream);

  (void)hipFuncSetAttribute((const void*)rnn_persist,
                            hipFuncAttributeMaxDynamicSharedMemorySize, LDS_DYN);

  void* args[7];
  args[0]=(void*)&x;    args[1]=(void*)&Wih;  args[2]=(void*)&Whh; args[3]=(void*)&bias;
  args[4]=(void*)&bn;   args[5]=(void*)&h_buf; args[6]=(void*)&mbox;
  hipError_t e = hipLaunchCooperativeKernel((const void*)rnn_persist,
                                            dim3(256), dim3(NT), args, LDS_DYN, stream);
  if (e != hipSuccess){
    (void)hipGetLastError();
    rnn_persist<<<dim3(256), dim3(NT), LDS_DYN, stream>>>(x, Wih, Whh, bias, bn, h_buf, mbox);
  }
  // T_ even -> final h in hb0; kernel boundary makes h_buf coherent for head_k
  head_k<<<dim3(128), dim3(64), 0, stream>>>(h_buf, Wout, bout, out);
}